// Round 9
// baseline (185.047 us; speedup 1.0000x reference)
//
#include <hip/hip_runtime.h>
#include <hip/hip_bf16.h>
#include <stdint.h>

// B=16, S=512, D=512, H=8, DH=64. Float tensors fp32; mask int32; out fp32.
// Internals: bf16 MFMA operands, fp32 accumulation.
// r23 = r22 (170.5us verified) with gemm_qkv A-operand DE-STAGED: A-frags read
//       global->VGPR (b128, 1-step register prefetch, counted vmcnt(6)); B keeps
//       the gload_lds double-buffer. Rationale: K-loop is LDS-read-throughput
//       bound (12 waves x 8 ds_read_b128 ~1152 cyc/CU-step vs 234 cyc MFMA, and
//       the 64B-row-stride frag reads are ~8-way bank-conflicted; pad/swizzle
//       blocked by gload_lds linear-dest). Halves LDS reads; bit-identical math.

typedef __hip_bfloat16 bf16;
typedef __bf16 bf16x8 __attribute__((ext_vector_type(8)));
typedef float f32x4 __attribute__((ext_vector_type(4)));

#define MFMA16(a, b, c) __builtin_amdgcn_mfma_f32_16x16x32_bf16((a), (b), (c), 0, 0, 0)

static __device__ __forceinline__ bf16 f2b(float v) { return __float2bfloat16(v); }
static __device__ __forceinline__ bf16x8 ld8(const bf16* p) { return *(const bf16x8*)p; }
static __device__ __forceinline__ uint16_t f2bu(float v) {
  return __hip_bfloat16_raw(__float2bfloat16(v)).x;
}
static __device__ __forceinline__ float bu2f(uint32_t u) {
  union { uint32_t i; float f; } c;
  c.i = u << 16;
  return c.f;
}
// m97-style async global->LDS, 16 B/lane (wave-uniform base + lane*16).
static __device__ __forceinline__ void stage16(const bf16* g, bf16* l) {
  __builtin_amdgcn_global_load_lds(
      (const __attribute__((address_space(1))) void*)g,
      (__attribute__((address_space(3))) void*)l, 16, 0, 0);
}

// ---------------------------------------------------------------- fused prep (grid-compressed)
// blocks 0..2047:    LN(x) -> h, one wave per row (4 rows/block), no barrier
// blocks 2048..6143: mask -> bitmask, 1024 elems/block (4 ballots/wave)
// blocks 6144..7167: weight transpose + cast (unchanged 32x32 tiles)
__global__ __launch_bounds__(256) void prep(
    const float* __restrict__ x, const float* __restrict__ lng,
    const float* __restrict__ lnb, bf16* __restrict__ h,
    const int* __restrict__ mask, uint32_t* __restrict__ bits,
    const float* __restrict__ W0, const float* __restrict__ W1,
    const float* __restrict__ W2, const float* __restrict__ W3,
    bf16* __restrict__ T0, bf16* __restrict__ T1,
    bf16* __restrict__ T2, bf16* __restrict__ T3) {
  __shared__ float t[32][33];
  const int bid = blockIdx.x;
  const int tid = threadIdx.x;
  const int w = tid >> 6, lane = tid & 63;

  if (bid < 2048) {  // -------- LayerNorm(x) -> h (bf16); wave = row
    int row = bid * 4 + w;
    const float* xr = x + (size_t)row * 512 + lane * 8;
    float4 v0 = *(const float4*)xr;
    float4 v1 = *(const float4*)(xr + 4);
    float s  = v0.x + v0.y + v0.z + v0.w + v1.x + v1.y + v1.z + v1.w;
    float s2 = v0.x * v0.x + v0.y * v0.y + v0.z * v0.z + v0.w * v0.w +
               v1.x * v1.x + v1.y * v1.y + v1.z * v1.z + v1.w * v1.w;
#pragma unroll
    for (int m = 1; m < 64; m <<= 1) {
      s += __shfl_xor(s, m);
      s2 += __shfl_xor(s2, m);
    }
    float mean = s * (1.0f / 512.0f);
    float var = s2 * (1.0f / 512.0f) - mean * mean;
    float rstd = rsqrtf(var + 1e-5f);
    const float4 g0 = *(const float4*)(lng + lane * 8);
    const float4 g1 = *(const float4*)(lng + lane * 8 + 4);
    const float4 b0 = *(const float4*)(lnb + lane * 8);
    const float4 b1 = *(const float4*)(lnb + lane * 8 + 4);
    union { uint16_t u[8]; bf16x8 v; } o;
    o.u[0] = f2bu((v0.x - mean) * rstd * g0.x + b0.x);
    o.u[1] = f2bu((v0.y - mean) * rstd * g0.y + b0.y);
    o.u[2] = f2bu((v0.z - mean) * rstd * g0.z + b0.z);
    o.u[3] = f2bu((v0.w - mean) * rstd * g0.w + b0.w);
    o.u[4] = f2bu((v1.x - mean) * rstd * g1.x + b1.x);
    o.u[5] = f2bu((v1.y - mean) * rstd * g1.y + b1.y);
    o.u[6] = f2bu((v1.z - mean) * rstd * g1.z + b1.z);
    o.u[7] = f2bu((v1.w - mean) * rstd * g1.w + b1.w);
    *(bf16x8*)(h + (size_t)row * 512 + lane * 8) = o.v;
  } else if (bid < 6144) {  // -------- mask -> bitmask (4 coalesced ballots/wave)
    size_t base = (size_t)(bid - 2048) * 1024 + w * 64 + lane;
#pragma unroll
    for (int it = 0; it < 4; it++) {
      size_t e = base + it * 256;
      int mv = mask[e];
      unsigned long long bal = __ballot(mv != 0);
      if (lane == 0) ((unsigned long long*)bits)[e >> 6] = bal;
    }
  } else {  // -------- weight transpose + cast
    int tt = bid - 6144;                  // 0..1023
    int wsel = tt >> 8, rem = tt & 255;
    int n0 = (rem & 15) * 32, k0 = (rem >> 4) * 32;
    const float* src; bf16* dst;
    switch (wsel) {
      case 0: src = W0; dst = T0; break;
      case 1: src = W1; dst = T1; break;
      case 2: src = W2; dst = T2; break;
      default: src = W3; dst = T3; break;
    }
    int tx = tid & 31, ty = tid >> 5;     // 32 x 8
#pragma unroll
    for (int i = 0; i < 4; i++) {
      int kk = ty * 4 + i;
      t[kk][tx] = src[(k0 + kk) * 512 + n0 + tx];
    }
    __syncthreads();
#pragma unroll
    for (int i = 0; i < 4; i++) {
      int nn = ty * 4 + i;
      dst[(n0 + nn) * 512 + k0 + tx] = f2b(t[tx][nn]);
    }
  }
}

// ---------------------------------------------------------------- QKV GEMM (A destaged, B dbuf)
// A-frags: global->VGPR b128 with one-step register prefetch (a_nxt). Lanes of
// an l16 group read 16 consecutive rows x 64B-contiguous (4 q4 lanes/row) ->
// every 64B line fully used. B: gload_lds double-buffer + counted vmcnt.
// vmcnt(6) = {2 B-stages + 4 A-loads} of tile kc+1 stay in flight.
__global__ __launch_bounds__(256) void gemm_qkv(
    const bf16* __restrict__ hm,
    const bf16* __restrict__ WT0, const bf16* __restrict__ WT1, const bf16* __restrict__ WT2,
    const float* __restrict__ bq, const float* __restrict__ bk, const float* __restrict__ bv,
    bf16* __restrict__ outq, bf16* __restrict__ outk, bf16* __restrict__ outvT) {
  const int sel = blockIdx.z;
  const bf16* WT = sel == 0 ? WT0 : (sel == 1 ? WT1 : WT2);
  const float* bias = sel == 0 ? bq : (sel == 1 ? bk : bv);
  __shared__ __align__(16) uint16_t SM[128 * 136];   // 34.8 KB; K-loop uses 16 KB (B dbuf)
  bf16* Bbuf = (bf16*)SM;   // [2][128*32]
  int tid = threadIdx.x;
  int w = tid >> 6, lane = tid & 63, q4 = lane >> 4, l16 = lane & 15;
  int wr = w >> 1, wc = w & 1;
  int m0 = blockIdx.x * 128, n0 = blockIdx.y * 128;
  f32x4 acc[4][4];
#pragma unroll
  for (int i = 0; i < 4; i++)
#pragma unroll
    for (int j = 0; j < 4; j++) acc[i][j] = (f32x4){0.f, 0.f, 0.f, 0.f};

  const int srow = tid >> 2, sc8 = (tid & 3) * 8;       // B staging coords
  const int srow1 = (256 + tid) >> 2, sc81 = ((256 + tid) & 3) * 8;
  const bf16* abase = hm + (size_t)(m0 + wr * 64 + l16) * 512 + q4 * 8;

  bf16x8 a_cur[4], a_nxt[4];

  // prologue: stage B tile 0 (2 gload_lds) + load A tile 0 into regs
  {
    bf16* Bs = Bbuf;
    stage16(&WT[(size_t)(n0 + srow) * 512 + sc8], &Bs[(size_t)tid * 8]);
    stage16(&WT[(size_t)(n0 + srow1) * 512 + sc81], &Bs[(size_t)(256 + tid) * 8]);
#pragma unroll
    for (int rt = 0; rt < 4; rt++)
      a_cur[rt] = ld8(abase + (size_t)(rt * 16) * 512);
  }

  int cur = 0;
  for (int kc = 0; kc < 16; kc++) {
    if (kc < 15) {  // issue next tile: B into buf^1 (LDS), A into a_nxt (regs)
      int k0 = (kc + 1) * 32;
      bf16* Bs = Bbuf + (cur ^ 1) * 4096;
      stage16(&WT[(size_t)(n0 + srow) * 512 + k0 + sc8], &Bs[(size_t)tid * 8]);
      stage16(&WT[(size_t)(n0 + srow1) * 512 + k0 + sc81], &Bs[(size_t)(256 + tid) * 8]);
#pragma unroll
      for (int rt = 0; rt < 4; rt++)
        a_nxt[rt] = ld8(abase + (size_t)(rt * 16) * 512 + k0);
      asm volatile("s_waitcnt vmcnt(6)" ::: "memory");  // tile-kc loads (B LDS + A regs) done
    } else {
      asm volatile("s_waitcnt vmcnt(0)" ::: "memory");  // drain last tile
    }
    __builtin_amdgcn_s_barrier();          // all waves' B(kc) LDS writes visible
    __builtin_amdgcn_sched_barrier(0);     // pin: nothing hoisted above
    {
      bf16* Bs = Bbuf + cur * 4096;
      bf16x8 bfr[4];
#pragma unroll
      for (int nt = 0; nt < 4; nt++)
        bfr[nt] = ld8(&Bs[(wc * 64 + nt * 16 + l16) * 32 + q4 * 8]);
#pragma unroll
      for (int rt = 0; rt < 4; rt++)
#pragma unroll
        for (int nt = 0; nt < 4; nt++) acc[rt][nt] = MFMA16(a_cur[rt], bfr[nt], acc[rt][nt]);
    }
    __builtin_amdgcn_sched_barrier(0);
    __builtin_amdgcn_s_barrier();          // B(cur) ds_reads retired -> safe to overwrite
#pragma unroll
    for (int rt = 0; rt < 4; rt++) a_cur[rt] = a_nxt[rt];
    cur ^= 1;
  }

  if (sel != 2) {
    const float scale = sel == 0 ? 0.125f : 1.0f;
#pragma unroll
    for (int rt = 0; rt < 4; rt++)
#pragma unroll
      for (int nt = 0; nt < 4; nt++) {
        int ncol = wc * 64 + nt * 16 + l16;
        float bsv = bias[n0 + ncol];
#pragma unroll
        for (int r = 0; r < 4; r++) {
          int mrow = wr * 64 + rt * 16 + q4 * 4 + r;
          SM[mrow * 136 + ncol] = f2bu((acc[rt][nt][r] + bsv) * scale);
        }
      }
    __syncthreads();
    bf16* dst = sel == 0 ? outq : outk;
#pragma unroll
    for (int p = 0; p < 8; p++) {
      int e = p * 256 + tid;
      int row = e >> 4, c8 = (e & 15) * 8;
      bf16x8 vv = *(bf16x8*)&SM[row * 136 + c8];
      int gm = m0 + row, b_ = gm >> 9, s_ = gm & 511;
      int n = n0 + c8, hh = n >> 6, dh = n & 63;
      *(bf16x8*)(dst + ((size_t)((b_ * 8 + hh) * 512 + s_)) * 64 + dh) = vv;
    }
  } else {
#pragma unroll
    for (int rt = 0; rt < 4; rt++)
#pragma unroll
      for (int nt = 0; nt < 4; nt++) {
        int ncol = wc * 64 + nt * 16 + l16;
        float bsv = bias[n0 + ncol];
        union { uint16_t q[4]; uint2 u; } pk;
#pragma unroll
        for (int r = 0; r < 4; r++) pk.q[r] = f2bu(acc[rt][nt][r] + bsv);
        *(uint2*)&SM[ncol * 136 + wr * 64 + rt * 16 + q4 * 4] = pk.u;
      }
    __syncthreads();
#pragma unroll
    for (int p = 0; p < 8; p++) {
      int e = p * 256 + tid;
      int nn = e >> 4, s8 = (e & 15) * 8;
      bf16x8 vv = *(bf16x8*)&SM[nn * 136 + s8];
      int n = n0 + nn, hh = n >> 6, dh = n & 63;
      int gm = m0 + s8, b_ = gm >> 9, s_ = gm & 511;
      *(bf16x8*)(outvT + ((size_t)((b_ * 8 + hh) * 64 + dh)) * 512 + s_) = vv;
    }
  }
}

// ---------------------------------------------------------------- fused attention (r16 exact)
// T14 async-stage split + T5 setprio; two-pass LN-softmax; LDS-staged K/V.
__global__ __launch_bounds__(256, 4) void attn_fused(
    const bf16* __restrict__ q, const bf16* __restrict__ k, const bf16* __restrict__ vT,
    const uint32_t* __restrict__ bits, const float* __restrict__ lg,
    const float* __restrict__ lb, bf16* __restrict__ ctx) {
  const int id = blockIdx.x;              // 0..1023
  const int xcd = id & 7;
  const int j = id >> 3;                  // 0..127
  const int mt = j & 7;                   // 8 m-tiles of 64 rows
  const int bh = ((j >> 3) << 3) | xcd;   // bh%8 == xcd
  const int m0 = mt * 64;
  const int b = bh >> 3, hh = bh & 7;
  const int tid = threadIdx.x;
  const int w = tid >> 6, lane = tid & 63, q4 = lane >> 4, l16 = lane & 15;

  __shared__ __align__(16) bf16 SBk[2][32 * 72];   // 9216 B  k chunk
  __shared__ __align__(16) bf16 SBv[2][64 * 40];   // 10240 B v chunk
  __shared__ uint32_t GB[512];                     // 2048 B {gamma,beta} bf16-packed
  __shared__ uint32_t sbits[64][17];               // 4352 B mask bits (padded)

  GB[tid] = (uint32_t)f2bu(lg[tid]) | ((uint32_t)f2bu(lb[tid]) << 16);
  GB[tid + 256] = (uint32_t)f2bu(lg[tid + 256]) | ((uint32_t)f2bu(lb[tid + 256]) << 16);
  {
    int row = tid >> 2, g = tid & 3;
    const uint32_t* src = bits + ((size_t)b * 512 + m0 + row) * 16 + g * 4;
    uint4 u = *(const uint4*)src;
    sbits[row][g * 4] = u.x; sbits[row][g * 4 + 1] = u.y;
    sbits[row][g * 4 + 2] = u.z; sbits[row][g * 4 + 3] = u.w;
  }

  const bf16* qb = q + ((size_t)bh * 512 + m0 + w * 16) * 64;
  const bf16* kb = k + (size_t)bh * 512 * 64;
  const bf16* vb = vT + (size_t)bh * 64 * 512;

  bf16x8 aq0 = ld8(qb + (size_t)l16 * 64 + q4 * 8);
  bf16x8 aq1 = ld8(qb + (size_t)l16 * 64 + 32 + q4 * 8);

  const int key0 = tid >> 3, dh8 = (tid & 7) * 8;   // K staging coords
  const int dhv = tid >> 2, kk8 = (tid & 3) * 8;    // V staging coords

  *(bf16x8*)&SBk[0][key0 * 72 + dh8] = ld8(kb + (size_t)key0 * 64 + dh8);
  __syncthreads();  // GB + sbits + k chunk 0

  // ---- phase 1: S^T stats only (per-lane row l16)
  float s = 0.f, s2 = 0.f;
  for (int c = 0; c < 16; c++) {
    const int buf = c & 1;
    bf16x8 rk;                            // T14: issue load early ...
    if (c < 15) rk = ld8(kb + (size_t)((c + 1) * 32 + key0) * 64 + dh8);
    __builtin_amdgcn_s_setprio(1);
#pragma unroll
    for (int kg = 0; kg < 2; kg++) {
      const bf16* kp = &SBk[buf][(kg * 16 + l16) * 72];
      bf16x8 b0 = ld8(kp + q4 * 8);
      bf16x8 b1 = ld8(kp + 32 + q4 * 8);
      f32x4 acc = (f32x4){0.f, 0.f, 0.f, 0.f};
      acc = MFMA16(b0, aq0, acc);   // A=k, B=q -> S^T[key][row]
      acc = MFMA16(b1, aq1, acc);
#pragma unroll
      for (int r = 0; r < 4; r++) {
        float v = acc[r];
        s += v;
        s2 += v * v;
      }
    }
    __builtin_amdgcn_s_setprio(0);
    if (c < 15)                           // ... write late, hidden by compute
      *(bf16x8*)&SBk[buf ^ 1][key0 * 72 + dh8] = rk;
    __syncthreads();
  }
  s += __shfl_xor(s, 16);  s += __shfl_xor(s, 32);
  s2 += __shfl_xor(s2, 16); s2 += __shfl_xor(s2, 32);
  const float mean = s * (1.0f / 512.0f);
  const float rstd = rsqrtf(s2 * (1.0f / 512.0f) - mean * mean + 1e-5f);

  // ---- phase 3: recompute S^T, LN+mask+exp in-lane, shuffle to A-layout, PV
  *(bf16x8*)&SBk[0][key0 * 72 + dh8] = ld8(kb + (size_t)key0 * 64 + dh8);
  *(bf16x8*)&SBv[0][dhv * 40 + kk8] = ld8(vb + (size_t)dhv * 512 + kk8);
  __syncthreads();

  f32x4 o[4];
#pragma unroll
  for (int nt = 0; nt < 4; nt++) o[nt] = (f32x4){0.f, 0.f, 0.f, 0.f};
  float se = 0.f;
  const int src0 = ((q4 & 1) * 2) * 16 + l16;
  const int src1 = src0 + 16;
  const bool hi = (q4 >> 1) != 0;

  for (int c = 0; c < 16; c++) {
    const int buf = c & 1;
    bf16x8 rk, rv;                        // T14: issue loads early ...
    if (c < 15) {
      rk = ld8(kb + (size_t)((c + 1) * 32 + key0) * 64 + dh8);
      rv = ld8(vb + (size_t)dhv * 512 + (c + 1) * 32 + kk8);
    }
    const uint32_t dw = sbits[w * 16 + l16][c];  // broadcast across q4
    uint32_t Pk[2][2];
#pragma unroll
    for (int kg = 0; kg < 2; kg++) {
      const bf16* kp = &SBk[buf][(kg * 16 + l16) * 72];
      bf16x8 b0 = ld8(kp + q4 * 8);
      bf16x8 b1 = ld8(kp + 32 + q4 * 8);
      f32x4 acc = (f32x4){0.f, 0.f, 0.f, 0.f};
      __builtin_amdgcn_s_setprio(1);
      acc = MFMA16(b0, aq0, acc);   // A=k, B=q -> S^T[key][row]
      acc = MFMA16(b1, aq1, acc);
      __builtin_amdgcn_s_setprio(0);
      uint4 gb4 = *(uint4*)&GB[c * 32 + kg * 16 + q4 * 4];  // 4 consecutive keys
      uint16_t p[4];
#pragma unroll
      for (int r = 0; r < 4; r++) {
        uint32_t gb = r == 0 ? gb4.x : (r == 1 ? gb4.y : (r == 2 ? gb4.z : gb4.w));
        float t = (acc[r] - mean) * rstd * bu2f(gb & 0xffffu) + bu2f(gb >> 16);
        t = ((dw >> (kg * 16 + q4 * 4 + r)) & 1u) ? t : -1.0e9f;
        float pf = __expf(t);
        se += pf;
        p[r] = f2bu(pf);
      }
      Pk[kg][0] = (uint32_t)p[0] | ((uint32_t)p[1] << 16);
      Pk[kg][1] = (uint32_t)p[2] | ((uint32_t)p[3] << 16);
    }
    uint32_t t00 = __shfl(Pk[0][0], src0), t01 = __shfl(Pk[1][0], src0);
    uint32_t t10 = __shfl(Pk[0][1], src0), t11 = __shfl(Pk[1][1], src0);
    uint32_t t20 = __shfl(Pk[0][0], src1), t21 = __shfl(Pk[1][0], src1);
    uint32_t t30 = __shfl(Pk[0][1], src1), t31 = __shfl(Pk[1][1], src1);
    union { uint32_t d[4]; bf16x8 v; } af;
    af.d[0] = hi ? t01 : t00;
    af.d[1] = hi ? t11 : t10;
    af.d[2] = hi ? t21 : t20;
    af.d[3] = hi ? t31 : t30;
    __builtin_amdgcn_s_setprio(1);
#pragma unroll
    for (int nt = 0; nt < 4; nt++) {
      bf16x8 bv8 = ld8(&SBv[buf][(nt * 16 + l16) * 40 + q4 * 8]);
      o[nt] = MFMA16(af.v, bv8, o[nt]);
    }
    __builtin_amdgcn_s_setprio(0);
    if (c < 15) {                         // ... write late, hidden by compute
      *(bf16x8*)&SBk[buf ^ 1][key0 * 72 + dh8] = rk;
      *(bf16x8*)&SBv[buf ^ 1][dhv * 40 + kk8] = rv;
    }
    __syncthreads();
  }

  se += __shfl_xor(se, 16);
  se += __shfl_xor(se, 32);
  float invr = 1.0f / se;
  float inv[4];
#pragma unroll
  for (int r = 0; r < 4; r++) inv[r] = __shfl(invr, q4 * 4 + r);

  bf16* cb = ctx + ((size_t)b * 512 + m0 + w * 16) * 512 + hh * 64;
#pragma unroll
  for (int nt = 0; nt < 4; nt++)
#pragma unroll
    for (int r = 0; r < 4; r++)
      cb[(size_t)(q4 * 4 + r) * 512 + nt * 16 + l16] = f2b(o[nt][r] * inv[r]);
}

// ---------------------------------------------------------------- out proj + residual (fp32 out)
// 64x128 tiles -> grid 512 = 2 blocks/CU.
__global__ __launch_bounds__(256) void gemm_out(
    const bf16* __restrict__ ctx, const bf16* __restrict__ WT,
    const float* __restrict__ bd, const float* __restrict__ x, float* __restrict__ out) {
  __shared__ __align__(16) bf16 As[64 * 32];
  __shared__ __align__(16) bf16 Bs[128 * 32];
  int tid = threadIdx.x;
  int w = tid >> 6, lane = tid & 63, q4 = lane >> 4, l16 = lane & 15;
  int m0 = blockIdx.x * 64, n0 = blockIdx.y * 128;
  f32x4 acc[4][2];
#pragma unroll
  for (int i = 0; i < 4; i++)
#pragma unroll
    for (int j = 0; j < 2; j++) acc[i][j] = (f32x4){0.f, 0.f, 0.f, 0.f};

  for (int kc = 0; kc < 16; kc++) {
    int k0 = kc * 32;
    {
      int e = tid;                        // A: 64x32 = 256 units
      int row = e >> 2, c8 = (e & 3) * 8;
      stage16(&ctx[(size_t)(m0 + row) * 512 + k0 + c8], &As[e * 8]);
    }
#pragma unroll
    for (int u0 = 0; u0 < 2; u0++) {      // B: 128x32 = 512 units
      int e = u0 * 256 + tid;
      int row = e >> 2, c8 = (e & 3) * 8;
      stage16(&WT[(size_t)(n0 + row) * 512 + k0 + c8], &Bs[e * 8]);
    }
    __syncthreads();
    bf16x8 af[4], bfr[2];
#pragma unroll
    for (int rt = 0; rt < 4; rt++)
      af[rt] = ld8(&As[(rt * 16 + l16) * 32 + q4 * 8]);
#pragma unroll
    for (int nt = 0; nt < 2; nt++)
      bfr[nt] = ld8(&Bs[(w * 32 + nt * 16 + l16) * 32 + q4 * 8]);
#pragma unroll
    for (int rt = 0; rt < 4; rt++)
#pragma unroll
      for (int nt = 0; nt < 2; nt++) acc[rt][nt] = MFMA16(af[rt], bfr[nt], acc[rt][nt]);
    __syncthreads();
  }
#pragma unroll
  for (int rt = 0; rt < 4; rt++) {
    int mbase = m0 + rt * 16 + q4 * 4;
#pragma unroll
    for (int nt = 0; nt < 2; nt++) {
      int n = n0 + w * 32 + nt * 16 + l16;
      float bsv = bd[n];
#pragma unroll
      for (int r = 0; r < 4; r++) {
        size_t idx = (size_t)(mbase + r) * 512 + n;
        out[idx] = acc[rt][nt][r] + bsv + x[idx];
      }
    }
  }
}

// ---------------------------------------------------------------- launch
extern "C" void kernel_launch(void* const* d_in, const int* in_sizes, int n_in,
                              void* d_out, int out_size, void* d_ws, size_t ws_size,
                              hipStream_t stream) {
  const float* x = (const float*)d_in[0];
  const int* mask = (const int*)d_in[1];
  const float* ln_g = (const float*)d_in[2];
  const float* ln_b = (const float*)d_in[3];
  const float* lna_g = (const float*)d_in[4];
  const float* lna_b = (const float*)d_in[5];
  const float* Wq = (const float*)d_in[6];
  const float* bq = (const float*)d_in[7];
  const float* Wk = (const float*)d_in[8];
  const float* bk = (const float*)d_in[9];
  const float* Wv = (const float*)d_in[10];
  const float* bv = (const float*)d_in[11];
  const float* Wd = (const float*)d_in[12];
  const float* bd = (const float*)d_in[13];

  char* ws = (char*)d_ws;
  const size_t MB = 1024 * 1024;
  if (ws_size < 44 * MB) return;
  bf16* h = (bf16*)(ws);                 // 8 MB  [8192,512]
  bf16* qd = (bf16*)(ws + 8 * MB);       // 8 MB  [B,H,S,DH]
  bf16* kd = (bf16*)(ws + 16 * MB);      // 8 MB  [B,H,S,DH]
  bf16* vTd = (bf16*)(ws + 24 * MB);     // 8 MB  [B,H,DH,S]
  bf16* ctx = (bf16*)(ws + 32 * MB);     // 8 MB  [B,S,D] bf16
  bf16* WqT = (bf16*)(ws + 40 * MB);
  bf16* WkT = (bf16*)(ws + 40 * MB + 512 * 1024);
  bf16* WvT = (bf16*)(ws + 40 * MB + 1024 * 1024);
  bf16* WdT = (bf16*)(ws + 40 * MB + 1536 * 1024);
  uint32_t* bits = (uint32_t*)(ws + 42 * MB);  // 512 KB

  prep<<<7168, 256, 0, stream>>>(x, ln_g, ln_b, h, mask, bits,
                                 Wq, Wk, Wv, Wd, WqT, WkT, WvT, WdT);
  gemm_qkv<<<dim3(64, 4, 3), 256, 0, stream>>>(h, WqT, WkT, WvT, bq, bk, bv, qd, kd, vTd);
  attn_fused<<<1024, 256, 0, stream>>>(qd, kd, vTd, bits, lna_g, lna_b, ctx);
  gemm_out<<<dim3(128, 4), 256, 0, stream>>>(ctx, WdT, bd, x, (float*)d_out);
}

// Round 10
// 169.789 us; speedup vs baseline: 1.0899x; 1.0899x over previous
//
#include <hip/hip_runtime.h>
#include <hip/hip_bf16.h>
#include <stdint.h>

// B=16, S=512, D=512, H=8, DH=64. Float tensors fp32; mask int32; out fp32.
// Internals: bf16 MFMA operands, fp32 accumulation.
// r24 = r22 (170.5us verified: prep grid-compressed + qkv counted-vmcnt dbuf +
//       attn T14/T5) with the SAME counted-vmcnt dbuf transform applied to
//       gemm_out (24KB LDS dbuf, vmcnt(3) steady-state). r23's A-destage
//       reverted (+14.5us: per-wave L2 reads beat by shared LDS path).

typedef __hip_bfloat16 bf16;
typedef __bf16 bf16x8 __attribute__((ext_vector_type(8)));
typedef float f32x4 __attribute__((ext_vector_type(4)));

#define MFMA16(a, b, c) __builtin_amdgcn_mfma_f32_16x16x32_bf16((a), (b), (c), 0, 0, 0)

static __device__ __forceinline__ bf16 f2b(float v) { return __float2bfloat16(v); }
static __device__ __forceinline__ bf16x8 ld8(const bf16* p) { return *(const bf16x8*)p; }
static __device__ __forceinline__ uint16_t f2bu(float v) {
  return __hip_bfloat16_raw(__float2bfloat16(v)).x;
}
static __device__ __forceinline__ float bu2f(uint32_t u) {
  union { uint32_t i; float f; } c;
  c.i = u << 16;
  return c.f;
}
// m97-style async global->LDS, 16 B/lane (wave-uniform base + lane*16).
static __device__ __forceinline__ void stage16(const bf16* g, bf16* l) {
  __builtin_amdgcn_global_load_lds(
      (const __attribute__((address_space(1))) void*)g,
      (__attribute__((address_space(3))) void*)l, 16, 0, 0);
}

// ---------------------------------------------------------------- fused prep (grid-compressed)
// blocks 0..2047:    LN(x) -> h, one wave per row (4 rows/block), no barrier
// blocks 2048..6143: mask -> bitmask, 1024 elems/block (4 ballots/wave)
// blocks 6144..7167: weight transpose + cast (unchanged 32x32 tiles)
__global__ __launch_bounds__(256) void prep(
    const float* __restrict__ x, const float* __restrict__ lng,
    const float* __restrict__ lnb, bf16* __restrict__ h,
    const int* __restrict__ mask, uint32_t* __restrict__ bits,
    const float* __restrict__ W0, const float* __restrict__ W1,
    const float* __restrict__ W2, const float* __restrict__ W3,
    bf16* __restrict__ T0, bf16* __restrict__ T1,
    bf16* __restrict__ T2, bf16* __restrict__ T3) {
  __shared__ float t[32][33];
  const int bid = blockIdx.x;
  const int tid = threadIdx.x;
  const int w = tid >> 6, lane = tid & 63;

  if (bid < 2048) {  // -------- LayerNorm(x) -> h (bf16); wave = row
    int row = bid * 4 + w;
    const float* xr = x + (size_t)row * 512 + lane * 8;
    float4 v0 = *(const float4*)xr;
    float4 v1 = *(const float4*)(xr + 4);
    float s  = v0.x + v0.y + v0.z + v0.w + v1.x + v1.y + v1.z + v1.w;
    float s2 = v0.x * v0.x + v0.y * v0.y + v0.z * v0.z + v0.w * v0.w +
               v1.x * v1.x + v1.y * v1.y + v1.z * v1.z + v1.w * v1.w;
#pragma unroll
    for (int m = 1; m < 64; m <<= 1) {
      s += __shfl_xor(s, m);
      s2 += __shfl_xor(s2, m);
    }
    float mean = s * (1.0f / 512.0f);
    float var = s2 * (1.0f / 512.0f) - mean * mean;
    float rstd = rsqrtf(var + 1e-5f);
    const float4 g0 = *(const float4*)(lng + lane * 8);
    const float4 g1 = *(const float4*)(lng + lane * 8 + 4);
    const float4 b0 = *(const float4*)(lnb + lane * 8);
    const float4 b1 = *(const float4*)(lnb + lane * 8 + 4);
    union { uint16_t u[8]; bf16x8 v; } o;
    o.u[0] = f2bu((v0.x - mean) * rstd * g0.x + b0.x);
    o.u[1] = f2bu((v0.y - mean) * rstd * g0.y + b0.y);
    o.u[2] = f2bu((v0.z - mean) * rstd * g0.z + b0.z);
    o.u[3] = f2bu((v0.w - mean) * rstd * g0.w + b0.w);
    o.u[4] = f2bu((v1.x - mean) * rstd * g1.x + b1.x);
    o.u[5] = f2bu((v1.y - mean) * rstd * g1.y + b1.y);
    o.u[6] = f2bu((v1.z - mean) * rstd * g1.z + b1.z);
    o.u[7] = f2bu((v1.w - mean) * rstd * g1.w + b1.w);
    *(bf16x8*)(h + (size_t)row * 512 + lane * 8) = o.v;
  } else if (bid < 6144) {  // -------- mask -> bitmask (4 coalesced ballots/wave)
    size_t base = (size_t)(bid - 2048) * 1024 + w * 64 + lane;
#pragma unroll
    for (int it = 0; it < 4; it++) {
      size_t e = base + it * 256;
      int mv = mask[e];
      unsigned long long bal = __ballot(mv != 0);
      if (lane == 0) ((unsigned long long*)bits)[e >> 6] = bal;
    }
  } else {  // -------- weight transpose + cast
    int tt = bid - 6144;                  // 0..1023
    int wsel = tt >> 8, rem = tt & 255;
    int n0 = (rem & 15) * 32, k0 = (rem >> 4) * 32;
    const float* src; bf16* dst;
    switch (wsel) {
      case 0: src = W0; dst = T0; break;
      case 1: src = W1; dst = T1; break;
      case 2: src = W2; dst = T2; break;
      default: src = W3; dst = T3; break;
    }
    int tx = tid & 31, ty = tid >> 5;     // 32 x 8
#pragma unroll
    for (int i = 0; i < 4; i++) {
      int kk = ty * 4 + i;
      t[kk][tx] = src[(k0 + kk) * 512 + n0 + tx];
    }
    __syncthreads();
#pragma unroll
    for (int i = 0; i < 4; i++) {
      int nn = ty * 4 + i;
      dst[(n0 + nn) * 512 + k0 + tx] = f2b(t[tx][nn]);
    }
  }
}

// ---------------------------------------------------------------- QKV GEMM (BK=32, dbuf + counted vmcnt)
// r22-exact (verified 170.5us). Tile kc+1 issued at iter top into buf^1,
// s_waitcnt vmcnt(4) waits only tile kc, raw s_barrier (no vmcnt(0) drain).
__global__ __launch_bounds__(256) void gemm_qkv(
    const bf16* __restrict__ hm,
    const bf16* __restrict__ WT0, const bf16* __restrict__ WT1, const bf16* __restrict__ WT2,
    const float* __restrict__ bq, const float* __restrict__ bk, const float* __restrict__ bv,
    bf16* __restrict__ outq, bf16* __restrict__ outk, bf16* __restrict__ outvT) {
  const int sel = blockIdx.z;
  const bf16* WT = sel == 0 ? WT0 : (sel == 1 ? WT1 : WT2);
  const float* bias = sel == 0 ? bq : (sel == 1 ? bk : bv);
  __shared__ __align__(16) uint16_t SM[128 * 136];   // 34.8 KB; K-loop dbuf uses 32 KB of it
  bf16* buf = (bf16*)SM;   // [d][As 4096 | Bs 4096] elements, d in {0,1}
  int tid = threadIdx.x;
  int w = tid >> 6, lane = tid & 63, q4 = lane >> 4, l16 = lane & 15;
  int wr = w >> 1, wc = w & 1;
  int m0 = blockIdx.x * 128, n0 = blockIdx.y * 128;
  f32x4 acc[4][4];
#pragma unroll
  for (int i = 0; i < 4; i++)
#pragma unroll
    for (int j = 0; j < 4; j++) acc[i][j] = (f32x4){0.f, 0.f, 0.f, 0.f};

  const int srow = tid >> 2, sc8 = (tid & 3) * 8;       // staging coords (e = tid, tid+256)
  const int srow1 = (256 + tid) >> 2, sc81 = ((256 + tid) & 3) * 8;

  // prologue: stage tile 0 into d=0 (4 loads in flight)
  {
    bf16* As = buf;
    bf16* Bs = buf + 4096;
    stage16(&hm[(size_t)(m0 + srow) * 512 + sc8], &As[(size_t)tid * 8]);
    stage16(&WT[(size_t)(n0 + srow) * 512 + sc8], &Bs[(size_t)tid * 8]);
    stage16(&hm[(size_t)(m0 + srow1) * 512 + sc81], &As[(size_t)(256 + tid) * 8]);
    stage16(&WT[(size_t)(n0 + srow1) * 512 + sc81], &Bs[(size_t)(256 + tid) * 8]);
  }

  int cur = 0;
  for (int kc = 0; kc < 16; kc++) {
    if (kc < 15) {  // issue next tile into buf^1; stays in flight across barriers
      int k0 = (kc + 1) * 32;
      bf16* As = buf + (cur ^ 1) * 8192;
      bf16* Bs = As + 4096;
      stage16(&hm[(size_t)(m0 + srow) * 512 + k0 + sc8], &As[(size_t)tid * 8]);
      stage16(&WT[(size_t)(n0 + srow) * 512 + k0 + sc8], &Bs[(size_t)tid * 8]);
      stage16(&hm[(size_t)(m0 + srow1) * 512 + k0 + sc81], &As[(size_t)(256 + tid) * 8]);
      stage16(&WT[(size_t)(n0 + srow1) * 512 + k0 + sc81], &Bs[(size_t)(256 + tid) * 8]);
      asm volatile("s_waitcnt vmcnt(4)" ::: "memory");  // own tile-kc loads done
    } else {
      asm volatile("s_waitcnt vmcnt(0)" ::: "memory");  // drain last tile
    }
    __builtin_amdgcn_s_barrier();          // all waves' tile-kc loads visible
    __builtin_amdgcn_sched_barrier(0);     // pin: no ds_read hoisted above
    {
      bf16* As = buf + cur * 8192;
      bf16* Bs = As + 4096;
      bf16x8 af[4], bfr[4];
#pragma unroll
      for (int rt = 0; rt < 4; rt++)
        af[rt] = ld8(&As[(wr * 64 + rt * 16 + l16) * 32 + q4 * 8]);
#pragma unroll
      for (int nt = 0; nt < 4; nt++)
        bfr[nt] = ld8(&Bs[(wc * 64 + nt * 16 + l16) * 32 + q4 * 8]);
#pragma unroll
      for (int rt = 0; rt < 4; rt++)
#pragma unroll
        for (int nt = 0; nt < 4; nt++) acc[rt][nt] = MFMA16(af[rt], bfr[nt], acc[rt][nt]);
    }
    __builtin_amdgcn_sched_barrier(0);
    __builtin_amdgcn_s_barrier();          // ds_reads of buf[cur] retired -> safe to overwrite
    cur ^= 1;
  }

  if (sel != 2) {
    const float scale = sel == 0 ? 0.125f : 1.0f;
#pragma unroll
    for (int rt = 0; rt < 4; rt++)
#pragma unroll
      for (int nt = 0; nt < 4; nt++) {
        int ncol = wc * 64 + nt * 16 + l16;
        float bsv = bias[n0 + ncol];
#pragma unroll
        for (int r = 0; r < 4; r++) {
          int mrow = wr * 64 + rt * 16 + q4 * 4 + r;
          SM[mrow * 136 + ncol] = f2bu((acc[rt][nt][r] + bsv) * scale);
        }
      }
    __syncthreads();
    bf16* dst = sel == 0 ? outq : outk;
#pragma unroll
    for (int p = 0; p < 8; p++) {
      int e = p * 256 + tid;
      int row = e >> 4, c8 = (e & 15) * 8;
      bf16x8 vv = *(bf16x8*)&SM[row * 136 + c8];
      int gm = m0 + row, b_ = gm >> 9, s_ = gm & 511;
      int n = n0 + c8, hh = n >> 6, dh = n & 63;
      *(bf16x8*)(dst + ((size_t)((b_ * 8 + hh) * 512 + s_)) * 64 + dh) = vv;
    }
  } else {
#pragma unroll
    for (int rt = 0; rt < 4; rt++)
#pragma unroll
      for (int nt = 0; nt < 4; nt++) {
        int ncol = wc * 64 + nt * 16 + l16;
        float bsv = bias[n0 + ncol];
        union { uint16_t q[4]; uint2 u; } pk;
#pragma unroll
        for (int r = 0; r < 4; r++) pk.q[r] = f2bu(acc[rt][nt][r] + bsv);
        *(uint2*)&SM[ncol * 136 + wr * 64 + rt * 16 + q4 * 4] = pk.u;
      }
    __syncthreads();
#pragma unroll
    for (int p = 0; p < 8; p++) {
      int e = p * 256 + tid;
      int nn = e >> 4, s8 = (e & 15) * 8;
      bf16x8 vv = *(bf16x8*)&SM[nn * 136 + s8];
      int n = n0 + nn, hh = n >> 6, dh = n & 63;
      int gm = m0 + s8, b_ = gm >> 9, s_ = gm & 511;
      *(bf16x8*)(outvT + ((size_t)((b_ * 8 + hh) * 64 + dh)) * 512 + s_) = vv;
    }
  }
}

// ---------------------------------------------------------------- fused attention (r16 exact)
// T14 async-stage split + T5 setprio; two-pass LN-softmax; LDS-staged K/V.
__global__ __launch_bounds__(256, 4) void attn_fused(
    const bf16* __restrict__ q, const bf16* __restrict__ k, const bf16* __restrict__ vT,
    const uint32_t* __restrict__ bits, const float* __restrict__ lg,
    const float* __restrict__ lb, bf16* __restrict__ ctx) {
  const int id = blockIdx.x;              // 0..1023
  const int xcd = id & 7;
  const int j = id >> 3;                  // 0..127
  const int mt = j & 7;                   // 8 m-tiles of 64 rows
  const int bh = ((j >> 3) << 3) | xcd;   // bh%8 == xcd
  const int m0 = mt * 64;
  const int b = bh >> 3, hh = bh & 7;
  const int tid = threadIdx.x;
  const int w = tid >> 6, lane = tid & 63, q4 = lane >> 4, l16 = lane & 15;

  __shared__ __align__(16) bf16 SBk[2][32 * 72];   // 9216 B  k chunk
  __shared__ __align__(16) bf16 SBv[2][64 * 40];   // 10240 B v chunk
  __shared__ uint32_t GB[512];                     // 2048 B {gamma,beta} bf16-packed
  __shared__ uint32_t sbits[64][17];               // 4352 B mask bits (padded)

  GB[tid] = (uint32_t)f2bu(lg[tid]) | ((uint32_t)f2bu(lb[tid]) << 16);
  GB[tid + 256] = (uint32_t)f2bu(lg[tid + 256]) | ((uint32_t)f2bu(lb[tid + 256]) << 16);
  {
    int row = tid >> 2, g = tid & 3;
    const uint32_t* src = bits + ((size_t)b * 512 + m0 + row) * 16 + g * 4;
    uint4 u = *(const uint4*)src;
    sbits[row][g * 4] = u.x; sbits[row][g * 4 + 1] = u.y;
    sbits[row][g * 4 + 2] = u.z; sbits[row][g * 4 + 3] = u.w;
  }

  const bf16* qb = q + ((size_t)bh * 512 + m0 + w * 16) * 64;
  const bf16* kb = k + (size_t)bh * 512 * 64;
  const bf16* vb = vT + (size_t)bh * 64 * 512;

  bf16x8 aq0 = ld8(qb + (size_t)l16 * 64 + q4 * 8);
  bf16x8 aq1 = ld8(qb + (size_t)l16 * 64 + 32 + q4 * 8);

  const int key0 = tid >> 3, dh8 = (tid & 7) * 8;   // K staging coords
  const int dhv = tid >> 2, kk8 = (tid & 3) * 8;    // V staging coords

  *(bf16x8*)&SBk[0][key0 * 72 + dh8] = ld8(kb + (size_t)key0 * 64 + dh8);
  __syncthreads();  // GB + sbits + k chunk 0

  // ---- phase 1: S^T stats only (per-lane row l16)
  float s = 0.f, s2 = 0.f;
  for (int c = 0; c < 16; c++) {
    const int buf = c & 1;
    bf16x8 rk;                            // T14: issue load early ...
    if (c < 15) rk = ld8(kb + (size_t)((c + 1) * 32 + key0) * 64 + dh8);
    __builtin_amdgcn_s_setprio(1);
#pragma unroll
    for (int kg = 0; kg < 2; kg++) {
      const bf16* kp = &SBk[buf][(kg * 16 + l16) * 72];
      bf16x8 b0 = ld8(kp + q4 * 8);
      bf16x8 b1 = ld8(kp + 32 + q4 * 8);
      f32x4 acc = (f32x4){0.f, 0.f, 0.f, 0.f};
      acc = MFMA16(b0, aq0, acc);   // A=k, B=q -> S^T[key][row]
      acc = MFMA16(b1, aq1, acc);
#pragma unroll
      for (int r = 0; r < 4; r++) {
        float v = acc[r];
        s += v;
        s2 += v * v;
      }
    }
    __builtin_amdgcn_s_setprio(0);
    if (c < 15)                           // ... write late, hidden by compute
      *(bf16x8*)&SBk[buf ^ 1][key0 * 72 + dh8] = rk;
    __syncthreads();
  }
  s += __shfl_xor(s, 16);  s += __shfl_xor(s, 32);
  s2 += __shfl_xor(s2, 16); s2 += __shfl_xor(s2, 32);
  const float mean = s * (1.0f / 512.0f);
  const float rstd = rsqrtf(s2 * (1.0f / 512.0f) - mean * mean + 1e-5f);

  // ---- phase 3: recompute S^T, LN+mask+exp in-lane, shuffle to A-layout, PV
  *(bf16x8*)&SBk[0][key0 * 72 + dh8] = ld8(kb + (size_t)key0 * 64 + dh8);
  *(bf16x8*)&SBv[0][dhv * 40 + kk8] = ld8(vb + (size_t)dhv * 512 + kk8);
  __syncthreads();

  f32x4 o[4];
#pragma unroll
  for (int nt = 0; nt < 4; nt++) o[nt] = (f32x4){0.f, 0.f, 0.f, 0.f};
  float se = 0.f;
  const int src0 = ((q4 & 1) * 2) * 16 + l16;
  const int src1 = src0 + 16;
  const bool hi = (q4 >> 1) != 0;

  for (int c = 0; c < 16; c++) {
    const int buf = c & 1;
    bf16x8 rk, rv;                        // T14: issue loads early ...
    if (c < 15) {
      rk = ld8(kb + (size_t)((c + 1) * 32 + key0) * 64 + dh8);
      rv = ld8(vb + (size_t)dhv * 512 + (c + 1) * 32 + kk8);
    }
    const uint32_t dw = sbits[w * 16 + l16][c];  // broadcast across q4
    uint32_t Pk[2][2];
#pragma unroll
    for (int kg = 0; kg < 2; kg++) {
      const bf16* kp = &SBk[buf][(kg * 16 + l16) * 72];
      bf16x8 b0 = ld8(kp + q4 * 8);
      bf16x8 b1 = ld8(kp + 32 + q4 * 8);
      f32x4 acc = (f32x4){0.f, 0.f, 0.f, 0.f};
      __builtin_amdgcn_s_setprio(1);
      acc = MFMA16(b0, aq0, acc);   // A=k, B=q -> S^T[key][row]
      acc = MFMA16(b1, aq1, acc);
      __builtin_amdgcn_s_setprio(0);
      uint4 gb4 = *(uint4*)&GB[c * 32 + kg * 16 + q4 * 4];  // 4 consecutive keys
      uint16_t p[4];
#pragma unroll
      for (int r = 0; r < 4; r++) {
        uint32_t gb = r == 0 ? gb4.x : (r == 1 ? gb4.y : (r == 2 ? gb4.z : gb4.w));
        float t = (acc[r] - mean) * rstd * bu2f(gb & 0xffffu) + bu2f(gb >> 16);
        t = ((dw >> (kg * 16 + q4 * 4 + r)) & 1u) ? t : -1.0e9f;
        float pf = __expf(t);
        se += pf;
        p[r] = f2bu(pf);
      }
      Pk[kg][0] = (uint32_t)p[0] | ((uint32_t)p[1] << 16);
      Pk[kg][1] = (uint32_t)p[2] | ((uint32_t)p[3] << 16);
    }
    uint32_t t00 = __shfl(Pk[0][0], src0), t01 = __shfl(Pk[1][0], src0);
    uint32_t t10 = __shfl(Pk[0][1], src0), t11 = __shfl(Pk[1][1], src0);
    uint32_t t20 = __shfl(Pk[0][0], src1), t21 = __shfl(Pk[1][0], src1);
    uint32_t t30 = __shfl(Pk[0][1], src1), t31 = __shfl(Pk[1][1], src1);
    union { uint32_t d[4]; bf16x8 v; } af;
    af.d[0] = hi ? t01 : t00;
    af.d[1] = hi ? t11 : t10;
    af.d[2] = hi ? t21 : t20;
    af.d[3] = hi ? t31 : t30;
    __builtin_amdgcn_s_setprio(1);
#pragma unroll
    for (int nt = 0; nt < 4; nt++) {
      bf16x8 bv8 = ld8(&SBv[buf][(nt * 16 + l16) * 40 + q4 * 8]);
      o[nt] = MFMA16(af.v, bv8, o[nt]);
    }
    __builtin_amdgcn_s_setprio(0);
    if (c < 15) {                         // ... write late, hidden by compute
      *(bf16x8*)&SBk[buf ^ 1][key0 * 72 + dh8] = rk;
      *(bf16x8*)&SBv[buf ^ 1][dhv * 40 + kk8] = rv;
    }
    __syncthreads();
  }

  se += __shfl_xor(se, 16);
  se += __shfl_xor(se, 32);
  float invr = 1.0f / se;
  float inv[4];
#pragma unroll
  for (int r = 0; r < 4; r++) inv[r] = __shfl(invr, q4 * 4 + r);

  bf16* cb = ctx + ((size_t)b * 512 + m0 + w * 16) * 512 + hh * 64;
#pragma unroll
  for (int nt = 0; nt < 4; nt++)
#pragma unroll
    for (int r = 0; r < 4; r++)
      cb[(size_t)(q4 * 4 + r) * 512 + nt * 16 + l16] = f2b(o[nt][r] * inv[r]);
}

// ---------------------------------------------------------------- out proj + residual (dbuf + counted vmcnt)
// 64x128 tiles, grid 512 = 2 blocks/CU. Same transform as gemm_qkv r22:
// tile kc+1 (1 A-stage + 2 B-stages) issued at iter top into buf^1,
// s_waitcnt vmcnt(3) keeps them in flight across the raw barriers.
__global__ __launch_bounds__(256) void gemm_out(
    const bf16* __restrict__ ctx, const bf16* __restrict__ WT,
    const float* __restrict__ bd, const float* __restrict__ x, float* __restrict__ out) {
  __shared__ __align__(16) bf16 buf[2][6144];   // [d][As 2048 | Bs 4096] = 24 KB
  int tid = threadIdx.x;
  int w = tid >> 6, lane = tid & 63, q4 = lane >> 4, l16 = lane & 15;
  int m0 = blockIdx.x * 64, n0 = blockIdx.y * 128;
  f32x4 acc[4][2];
#pragma unroll
  for (int i = 0; i < 4; i++)
#pragma unroll
    for (int j = 0; j < 2; j++) acc[i][j] = (f32x4){0.f, 0.f, 0.f, 0.f};

  const int arow = tid >> 2, ac8 = (tid & 3) * 8;        // A staging (256 units)
  const int brow0 = tid >> 2, bc80 = (tid & 3) * 8;      // B staging u0=0
  const int brow1 = (256 + tid) >> 2, bc81 = ((256 + tid) & 3) * 8;  // B u0=1

  // prologue: stage tile 0 into d=0 (3 loads in flight)
  {
    bf16* As = buf[0];
    bf16* Bs = buf[0] + 2048;
    stage16(&ctx[(size_t)(m0 + arow) * 512 + ac8], &As[(size_t)tid * 8]);
    stage16(&WT[(size_t)(n0 + brow0) * 512 + bc80], &Bs[(size_t)tid * 8]);
    stage16(&WT[(size_t)(n0 + brow1) * 512 + bc81], &Bs[(size_t)(256 + tid) * 8]);
  }

  int cur = 0;
  for (int kc = 0; kc < 16; kc++) {
    if (kc < 15) {  // issue next tile into buf^1; stays in flight across barriers
      int k0 = (kc + 1) * 32;
      bf16* As = buf[cur ^ 1];
      bf16* Bs = As + 2048;
      stage16(&ctx[(size_t)(m0 + arow) * 512 + k0 + ac8], &As[(size_t)tid * 8]);
      stage16(&WT[(size_t)(n0 + brow0) * 512 + k0 + bc80], &Bs[(size_t)tid * 8]);
      stage16(&WT[(size_t)(n0 + brow1) * 512 + k0 + bc81], &Bs[(size_t)(256 + tid) * 8]);
      asm volatile("s_waitcnt vmcnt(3)" ::: "memory");  // own tile-kc loads done
    } else {
      asm volatile("s_waitcnt vmcnt(0)" ::: "memory");  // drain last tile
    }
    __builtin_amdgcn_s_barrier();          // all waves' tile-kc loads visible
    __builtin_amdgcn_sched_barrier(0);
    {
      bf16* As = buf[cur];
      bf16* Bs = As + 2048;
      bf16x8 af[4], bfr[2];
#pragma unroll
      for (int rt = 0; rt < 4; rt++)
        af[rt] = ld8(&As[(rt * 16 + l16) * 32 + q4 * 8]);
#pragma unroll
      for (int nt = 0; nt < 2; nt++)
        bfr[nt] = ld8(&Bs[(w * 32 + nt * 16 + l16) * 32 + q4 * 8]);
#pragma unroll
      for (int rt = 0; rt < 4; rt++)
#pragma unroll
        for (int nt = 0; nt < 2; nt++) acc[rt][nt] = MFMA16(af[rt], bfr[nt], acc[rt][nt]);
    }
    __builtin_amdgcn_sched_barrier(0);
    __builtin_amdgcn_s_barrier();          // ds_reads of buf[cur] retired -> safe to overwrite
    cur ^= 1;
  }
#pragma unroll
  for (int rt = 0; rt < 4; rt++) {
    int mbase = m0 + rt * 16 + q4 * 4;
#pragma unroll
    for (int nt = 0; nt < 2; nt++) {
      int n = n0 + w * 32 + nt * 16 + l16;
      float bsv = bd[n];
#pragma unroll
      for (int r = 0; r < 4; r++) {
        size_t idx = (size_t)(mbase + r) * 512 + n;
        out[idx] = acc[rt][nt][r] + bsv + x[idx];
      }
    }
  }
}

// ---------------------------------------------------------------- launch
extern "C" void kernel_launch(void* const* d_in, const int* in_sizes, int n_in,
                              void* d_out, int out_size, void* d_ws, size_t ws_size,
                              hipStream_t stream) {
  const float* x = (const float*)d_in[0];
  const int* mask = (const int*)d_in[1];
  const float* ln_g = (const float*)d_in[2];
  const float* ln_b = (const float*)d_in[3];
  const float* lna_g = (const float*)d_in[4];
  const float* lna_b = (const float*)d_in[5];
  const float* Wq = (const float*)d_in[6];
  const float* bq = (const float*)d_in[7];
  const float* Wk = (const float*)d_in[8];
  const float* bk = (const float*)d_in[9];
  const float* Wv = (const float*)d_in[10];
  const float* bv = (const float*)d_in[11];
  const float* Wd = (const float*)d_in[12];
  const float* bd = (const float*)d_in[13];

  char* ws = (char*)d_ws;
  const size_t MB = 1024 * 1024;
  if (ws_size < 44 * MB) return;
  bf16* h = (bf16*)(ws);                 // 8 MB  [8192,512]
  bf16* qd = (bf16*)(ws + 8 * MB);       // 8 MB  [B,H,S,DH]
  bf16* kd = (bf16*)(ws + 16 * MB);      // 8 MB  [B,H,S,DH]
  bf16* vTd = (bf16*)(ws + 24 * MB);     // 8 MB  [B,H,DH,S]
  bf16* ctx = (bf16*)(ws + 32 * MB);     // 8 MB  [B,S,D] bf16
  bf16* WqT = (bf16*)(ws + 40 * MB);
  bf16* WkT = (bf16*)(ws + 40 * MB + 512 * 1024);
  bf16* WvT = (bf16*)(ws + 40 * MB + 1024 * 1024);
  bf16* WdT = (bf16*)(ws + 40 * MB + 1536 * 1024);
  uint32_t* bits = (uint32_t*)(ws + 42 * MB);  // 512 KB

  prep<<<7168, 256, 0, stream>>>(x, ln_g, ln_b, h, mask, bits,
                                 Wq, Wk, Wv, Wd, WqT, WkT, WvT, WdT);
  gemm_qkv<<<dim3(64, 4, 3), 256, 0, stream>>>(h, WqT, WkT, WvT, bq, bk, bv, qd, kd, vTd);
  attn_fused<<<1024, 256, 0, stream>>>(qd, kd, vTd, bits, lna_g, lna_b, ctx);
  gemm_out<<<dim3(128, 4), 256, 0, stream>>>(ctx, WdT, bd, x, (float*)d_out);
}